// Round 1
// baseline (834.269 us; speedup 1.0000x reference)
//
#include <hip/hip_runtime.h>
#include <hip/hip_cooperative_groups.h>

namespace cg = cooperative_groups;

#define H 1024
#define V 50257
#define L 4096
#define NB 256            // blocks = CUs, 1 block/CU (cooperative residency)
#define NT 512            // threads/block -> 8 waves
#define NW 8              // waves/block
#define GWAVES (NB * NW)  // 2048 waves total
#define ROWS2 (L / NB)    // 16 attention rows per block

__device__ __forceinline__ float sigmoidf_(float x) { return 1.f / (1.f + expf(-x)); }

__device__ __forceinline__ float dot4(float4 w, float4 c) {
    return w.x * c.x + w.y * c.y + w.z * c.z + w.w * c.w;
}

// One cooperative megakernel. Phases separated by grid.sync():
//  P0 GRU (split-K, 2 waves per output j)         -> concat[H..2H), out[V..V+H)
//  P1 scores + per-block max                      -> scores[4096], bmax[256]
//  P2 global max M, e = exp(s-M) (16 rows/block)  -> eL (LDS), Sb[256]
//  P3 S, attn = e/S, ctx partial (float2/thread)  -> partial[256][1024]
//  P4 ctx reduce, 4 cols/block                    -> concat[0..H)
//  P5 logits GEMV + online per-block LSE          -> logits[V], red[2*256]
//  P6 LSE finalize + write log_softmax            -> out[0..V)
__global__ __launch_bounds__(NT, 1) void k_mega(
        const int* __restrict__ idx, const float* __restrict__ hidden,
        const float* __restrict__ enc, const float* __restrict__ emb,
        const float* __restrict__ w_ih, const float* __restrict__ w_hh,
        const float* __restrict__ b_ih, const float* __restrict__ b_hh,
        const float* __restrict__ out_w, const float* __restrict__ out_b,
        float* __restrict__ out, float* __restrict__ ws) {
    cg::grid_group grid = cg::this_grid();
    const int t = threadIdx.x;
    const int w = t >> 6, lane = t & 63;
    const int bid = blockIdx.x;
    const int gw = bid * NW + w;

    float* concat  = ws;               // [2048] ctx | h_new
    float* scores  = ws + 2048;        // [4096]
    float* Sb      = ws + 6144;        // [256]
    float* bmax    = ws + 6400;        // [256]
    float* red     = ws + 6656;        // [512] m[256] | s[256]
    float* partial = ws + 8192;        // [256*1024]
    float* logits  = ws + 8192 + NB * H; // [50257]

    __shared__ float gpart[NW][6];
    __shared__ float wmax_s[NW];
    __shared__ float eL[ROWS2];
    __shared__ float aL[ROWS2];
    __shared__ float mw[NW], sw[NW];
    __shared__ float sScalar;          // reused: M, then S, then C

    // ---------------- P0: GRU. j = bid*4 + (w>>1), two waves split K ---------
    {
        const int j = bid * 4 + (w >> 1);
        const int half = w & 1;
        const float* x   = emb + (size_t)idx[0] * H;
        const float* wir = w_ih + (size_t)j * H;
        const float* wiz = wir + (size_t)H * H;
        const float* win = wiz + (size_t)H * H;
        const float* whr = w_hh + (size_t)j * H;
        const float* whz = whr + (size_t)H * H;
        const float* whn = whz + (size_t)H * H;
        float sir = 0, siz = 0, sin_ = 0, shr = 0, shz = 0, shn = 0;
        #pragma unroll
        for (int it = 0; it < 2; ++it) {
            int elem = half * 512 + (it * 64 + lane) * 4;
            float4 xf = *(const float4*)(x + elem);
            float4 hf = *(const float4*)(hidden + elem);
            sir  += dot4(*(const float4*)(wir + elem), xf);
            siz  += dot4(*(const float4*)(wiz + elem), xf);
            sin_ += dot4(*(const float4*)(win + elem), xf);
            shr  += dot4(*(const float4*)(whr + elem), hf);
            shz  += dot4(*(const float4*)(whz + elem), hf);
            shn  += dot4(*(const float4*)(whn + elem), hf);
        }
        #pragma unroll
        for (int off = 32; off; off >>= 1) {
            sir += __shfl_xor(sir, off); siz += __shfl_xor(siz, off);
            sin_ += __shfl_xor(sin_, off); shr += __shfl_xor(shr, off);
            shz += __shfl_xor(shz, off); shn += __shfl_xor(shn, off);
        }
        if (lane == 0) {
            gpart[w][0] = sir; gpart[w][1] = siz; gpart[w][2] = sin_;
            gpart[w][3] = shr; gpart[w][4] = shz; gpart[w][5] = shn;
        }
    }
    __syncthreads();
    if (lane == 0 && (w & 1) == 0) {
        const int j = bid * 4 + (w >> 1);
        float sir = gpart[w][0] + gpart[w + 1][0];
        float siz = gpart[w][1] + gpart[w + 1][1];
        float sin_ = gpart[w][2] + gpart[w + 1][2];
        float shr = gpart[w][3] + gpart[w + 1][3];
        float shz = gpart[w][4] + gpart[w + 1][4];
        float shn = gpart[w][5] + gpart[w + 1][5];
        float r = sigmoidf_(sir + b_ih[j]       + shr + b_hh[j]);
        float z = sigmoidf_(siz + b_ih[H + j]   + shz + b_hh[H + j]);
        float n = tanhf(sin_ + b_ih[2 * H + j] + r * (shn + b_hh[2 * H + j]));
        float hn = (1.f - z) * n + z * hidden[j];
        concat[H + j] = hn;
        out[V + j] = hn;
    }
    grid.sync();

    // ---------------- P1: scores, 2 rows per wave + block max ----------------
    {
        const float* h = concat + H;
        float wmax = -INFINITY;
        #pragma unroll
        for (int r = 0; r < 2; ++r) {
            const int l = gw + r * GWAVES;
            const float* row = enc + (size_t)l * H;
            float s = 0.f;
            #pragma unroll
            for (int it = 0; it < 4; ++it) {
                int elem = (it * 64 + lane) * 4;
                s += dot4(*(const float4*)(row + elem), *(const float4*)(h + elem));
            }
            #pragma unroll
            for (int off = 32; off; off >>= 1) s += __shfl_xor(s, off);
            if (lane == 0) scores[l] = s;
            wmax = fmaxf(wmax, s);
        }
        if (lane == 0) wmax_s[w] = wmax;
    }
    __syncthreads();
    if (t == 0) {
        float m = wmax_s[0];
        #pragma unroll
        for (int k = 1; k < NW; ++k) m = fmaxf(m, wmax_s[k]);
        bmax[bid] = m;
    }
    grid.sync();

    // ---------------- P2: global max, e = exp(s - M), Sb ---------------------
    if (w == 0) {
        float m = fmaxf(fmaxf(bmax[lane], bmax[lane + 64]),
                        fmaxf(bmax[lane + 128], bmax[lane + 192]));
        #pragma unroll
        for (int off = 32; off; off >>= 1) m = fmaxf(m, __shfl_xor(m, off));
        if (lane == 0) sScalar = m;
    }
    __syncthreads();
    {
        const float M = sScalar;
        const int r0 = bid * ROWS2;
        if (t < ROWS2) eL[t] = expf(scores[r0 + t] - M);
    }
    __syncthreads();
    if (t == 0) {
        float s = 0.f;
        #pragma unroll
        for (int k = 0; k < ROWS2; ++k) s += eL[k];
        Sb[bid] = s;
    }
    grid.sync();

    // ---------------- P3: S, normalize, ctx partial --------------------------
    if (w == 0) {
        float s = Sb[lane] + Sb[lane + 64] + Sb[lane + 128] + Sb[lane + 192];
        #pragma unroll
        for (int off = 32; off; off >>= 1) s += __shfl_xor(s, off);
        if (lane == 0) sScalar = s;
    }
    __syncthreads();
    {
        const float invS = 1.f / sScalar;
        if (t < ROWS2) aL[t] = eL[t] * invS;
    }
    __syncthreads();
    {
        const int r0 = bid * ROWS2;
        float2 acc = make_float2(0.f, 0.f);
        const float* pbase = enc + (size_t)r0 * H + 2 * t;
        #pragma unroll
        for (int l = 0; l < ROWS2; ++l) {
            float2 v = *(const float2*)(pbase + (size_t)l * H);
            float a = aL[l];
            acc.x += a * v.x; acc.y += a * v.y;
        }
        *(float2*)(partial + (size_t)bid * H + 2 * t) = acc;
    }
    grid.sync();

    // ---------------- P4: ctx reduce, 4 cols per block -----------------------
    if (w < 4) {
        const int c = bid * 4 + w;
        float s = 0.f;
        #pragma unroll
        for (int k = 0; k < 4; ++k)
            s += partial[(size_t)(lane + 64 * k) * H + c];
        #pragma unroll
        for (int off = 32; off; off >>= 1) s += __shfl_xor(s, off);
        if (lane == 0) concat[c] = s;
    }
    grid.sync();

    // ---------------- P5: logits GEMV + online per-block LSE -----------------
    {
        float4 cv[8];
        #pragma unroll
        for (int it = 0; it < 8; ++it)
            cv[it] = *(const float4*)(concat + (it * 64 + lane) * 4);
        float lm = -INFINITY, ls = 0.f;
        for (int v = gw; v < V; v += GWAVES) {
            const float* row = out_w + (size_t)v * (2 * H);
            float s = 0.f;
            #pragma unroll
            for (int it = 0; it < 8; ++it) {
                int elem = (it * 64 + lane) * 4;
                s += dot4(*(const float4*)(row + elem), cv[it]);
            }
            #pragma unroll
            for (int off = 32; off; off >>= 1) s += __shfl_xor(s, off);
            s += out_b[v];
            if (lane == 0) logits[v] = s;
            float Mn = fmaxf(lm, s);
            ls = ls * expf(lm - Mn) + expf(s - Mn);
            lm = Mn;
        }
        if (lane == 0) { mw[w] = lm; sw[w] = ls; }
    }
    __syncthreads();
    if (t == 0) {
        float m = mw[0], s = sw[0];
        #pragma unroll
        for (int k = 1; k < NW; ++k) {
            float Mn = fmaxf(m, mw[k]);
            s = s * expf(m - Mn) + sw[k] * expf(mw[k] - Mn);
            m = Mn;
        }
        red[bid] = m;
        red[NB + bid] = s;
    }
    grid.sync();

    // ---------------- P6: LSE finalize + write -------------------------------
    if (w == 0) {
        float m = -INFINITY, s = 0.f;
        #pragma unroll
        for (int k = 0; k < 4; ++k) {
            int i = lane + 64 * k;
            float m2 = red[i], s2 = red[NB + i];
            float Mn = fmaxf(m, m2);
            s = s * expf(m - Mn) + s2 * expf(m2 - Mn);
            m = Mn;
        }
        #pragma unroll
        for (int off = 32; off; off >>= 1) {
            float m2 = __shfl_xor(m, off), s2 = __shfl_xor(s, off);
            float Mn = fmaxf(m, m2);
            s = s * expf(m - Mn) + s2 * expf(m2 - Mn);
            m = Mn;
        }
        if (lane == 0) sScalar = m + logf(s);
    }
    __syncthreads();
    {
        const float C = sScalar;
        const int v = bid * NT + t;
        if (v < V) out[v] = logits[v] - C;
    }
}

extern "C" void kernel_launch(void* const* d_in, const int* in_sizes, int n_in,
                              void* d_out, int out_size, void* d_ws, size_t ws_size,
                              hipStream_t stream) {
    const int*   idx    = (const int*)d_in[0];
    const float* hidden = (const float*)d_in[1];
    const float* enc    = (const float*)d_in[2];
    const float* emb    = (const float*)d_in[3];
    const float* w_ih   = (const float*)d_in[4];
    const float* w_hh   = (const float*)d_in[5];
    const float* b_ih   = (const float*)d_in[6];
    const float* b_hh   = (const float*)d_in[7];
    const float* out_w  = (const float*)d_in[8];
    const float* out_b  = (const float*)d_in[9];
    float* out = (float*)d_out;
    float* ws  = (float*)d_ws;

    void* args[] = { (void*)&idx, (void*)&hidden, (void*)&enc, (void*)&emb,
                     (void*)&w_ih, (void*)&w_hh, (void*)&b_ih, (void*)&b_hh,
                     (void*)&out_w, (void*)&out_b, (void*)&out, (void*)&ws };
    hipLaunchCooperativeKernel((void*)k_mega, dim3(NB), dim3(NT), args, 0, stream);
}

// Round 2
// 675.573 us; speedup vs baseline: 1.2349x; 1.2349x over previous
//
#include <hip/hip_runtime.h>

#define H 1024
#define V 50257
#define L 4096

__device__ __forceinline__ float sigmoidf_(float x) { return 1.f / (1.f + expf(-x)); }

__device__ __forceinline__ float dot4(float4 w, float4 c) {
    return w.x * c.x + w.y * c.y + w.z * c.z + w.w * c.w;
}

// monotone float<->uint map so atomicMax(uint) == float max
__device__ __forceinline__ unsigned int fkey(float f) {
    unsigned int u = __float_as_uint(f);
    return (u & 0x80000000u) ? ~u : (u | 0x80000000u);
}
__device__ __forceinline__ float finv(unsigned int k) {
    return (k & 0x80000000u) ? __uint_as_float(k & 0x7FFFFFFFu) : __uint_as_float(~k);
}

// ---------------- K1: GRU, split-K x2. grid=512 x 256 (2 outputs j / block) --
__global__ __launch_bounds__(256) void k_gru(const int* __restrict__ idx,
        const float* __restrict__ hidden, const float* __restrict__ emb,
        const float* __restrict__ w_ih, const float* __restrict__ w_hh,
        const float* __restrict__ b_ih, const float* __restrict__ b_hh,
        float* __restrict__ concat, float* __restrict__ out_h,
        unsigned int* __restrict__ gmax) {
    __shared__ float gpart[4][6];
    const int t = threadIdx.x, w = t >> 6, lane = t & 63;
    const int j = blockIdx.x * 2 + (w >> 1);
    const int half = w & 1;
    if (blockIdx.x == 0 && t == 0) *gmax = 0u;   // init for K2's atomicMax
    const float* x   = emb + (size_t)idx[0] * H;
    const float* wir = w_ih + (size_t)j * H;
    const float* wiz = wir + (size_t)H * H;
    const float* win = wiz + (size_t)H * H;
    const float* whr = w_hh + (size_t)j * H;
    const float* whz = whr + (size_t)H * H;
    const float* whn = whz + (size_t)H * H;
    float sir = 0, siz = 0, sin_ = 0, shr = 0, shz = 0, shn = 0;
    #pragma unroll
    for (int it = 0; it < 2; ++it) {
        int elem = half * 512 + (it * 64 + lane) * 4;
        float4 xf = *(const float4*)(x + elem);
        float4 hf = *(const float4*)(hidden + elem);
        sir  += dot4(*(const float4*)(wir + elem), xf);
        siz  += dot4(*(const float4*)(wiz + elem), xf);
        sin_ += dot4(*(const float4*)(win + elem), xf);
        shr  += dot4(*(const float4*)(whr + elem), hf);
        shz  += dot4(*(const float4*)(whz + elem), hf);
        shn  += dot4(*(const float4*)(whn + elem), hf);
    }
    #pragma unroll
    for (int off = 32; off; off >>= 1) {
        sir += __shfl_xor(sir, off); siz += __shfl_xor(siz, off);
        sin_ += __shfl_xor(sin_, off); shr += __shfl_xor(shr, off);
        shz += __shfl_xor(shz, off); shn += __shfl_xor(shn, off);
    }
    if (lane == 0) {
        gpart[w][0] = sir; gpart[w][1] = siz; gpart[w][2] = sin_;
        gpart[w][3] = shr; gpart[w][4] = shz; gpart[w][5] = shn;
    }
    __syncthreads();
    if (lane == 0 && half == 0) {
        float a0 = gpart[w][0] + gpart[w + 1][0];
        float a1 = gpart[w][1] + gpart[w + 1][1];
        float a2 = gpart[w][2] + gpart[w + 1][2];
        float a3 = gpart[w][3] + gpart[w + 1][3];
        float a4 = gpart[w][4] + gpart[w + 1][4];
        float a5 = gpart[w][5] + gpart[w + 1][5];
        float r = sigmoidf_(a0 + b_ih[j]       + a3 + b_hh[j]);
        float z = sigmoidf_(a1 + b_ih[H + j]   + a4 + b_hh[H + j]);
        float n = tanhf(a2 + b_ih[2 * H + j] + r * (a5 + b_hh[2 * H + j]));
        float hn = (1.f - z) * n + z * hidden[j];
        concat[H + j] = hn;
        out_h[j] = hn;
    }
}

// ---------------- K2: scores + global max via atomic. grid=1024 x 256 --------
__global__ __launch_bounds__(256) void k_scores(const float* __restrict__ enc,
        const float* __restrict__ concat, float* __restrict__ scores,
        unsigned int* __restrict__ gmax) {
    __shared__ float wm[4];
    const int w = threadIdx.x >> 6, lane = threadIdx.x & 63;
    const int l = blockIdx.x * 4 + w;
    const float* row = enc + (size_t)l * H;
    const float* h = concat + H;
    float s = 0.f;
    #pragma unroll
    for (int it = 0; it < 4; ++it) {
        int elem = (it * 64 + lane) * 4;
        s += dot4(*(const float4*)(row + elem), *(const float4*)(h + elem));
    }
    #pragma unroll
    for (int off = 32; off; off >>= 1) s += __shfl_xor(s, off);
    if (lane == 0) { scores[l] = s; wm[w] = s; }
    __syncthreads();
    if (threadIdx.x == 0) {
        float m = fmaxf(fmaxf(wm[0], wm[1]), fmaxf(wm[2], wm[3]));
        atomicMax(gmax, fkey(m));
    }
}

// ------ K3: unnormalized ctx partials + per-block sum(e). grid=256 x 256 -----
__global__ __launch_bounds__(256) void k_ctx_partial(const float* __restrict__ enc,
        const float* __restrict__ scores, const unsigned int* __restrict__ gmax,
        float* __restrict__ partial, float* __restrict__ sb) {
    __shared__ float eL[16];
    const int t = threadIdx.x;
    const int r0 = blockIdx.x * 16;
    if (t < 16) eL[t] = expf(scores[r0 + t] - finv(*gmax));
    __syncthreads();
    if (t == 0) {
        float s = 0.f;
        #pragma unroll
        for (int k = 0; k < 16; ++k) s += eL[k];
        sb[blockIdx.x] = s;
    }
    float acc0 = 0, acc1 = 0, acc2 = 0, acc3 = 0;
    const float* p = enc + (size_t)r0 * H + t * 4;
    #pragma unroll
    for (int l = 0; l < 16; ++l) {
        float4 v = *(const float4*)(p + (size_t)l * H);
        float e = eL[l];
        acc0 += e * v.x; acc1 += e * v.y; acc2 += e * v.z; acc3 += e * v.w;
    }
    *(float4*)(partial + (size_t)blockIdx.x * H + t * 4) = make_float4(acc0, acc1, acc2, acc3);
}

// ---------------- K4: reduce partials, divide by S. grid=4 x 256 -------------
__global__ __launch_bounds__(256) void k_ctx_reduce(const float* __restrict__ partial,
        const float* __restrict__ sb, float* __restrict__ concat) {
    __shared__ float sS[4];
    const int t = threadIdx.x, w = t >> 6, lane = t & 63;
    float s = sb[t];
    #pragma unroll
    for (int off = 32; off; off >>= 1) s += __shfl_xor(s, off);
    if (lane == 0) sS[w] = s;
    __syncthreads();
    const float invS = 1.f / (sS[0] + sS[1] + sS[2] + sS[3]);
    const int c = blockIdx.x * 256 + t;
    float acc = 0.f;
    #pragma unroll 8
    for (int b = 0; b < 256; ++b) acc += partial[(size_t)b * H + c];
    concat[c] = acc * invS;
}

// ------- K5: logits GEMV + fused per-block online LSE. grid=2048 x 256 -------
__global__ __launch_bounds__(256) void k_logits(const float* __restrict__ out_w,
        const float* __restrict__ out_b, const float* __restrict__ concat,
        float* __restrict__ logits, float* __restrict__ red) {
    __shared__ float mw[4], sw[4];
    const int w = threadIdx.x >> 6, lane = threadIdx.x & 63;
    const int gw = blockIdx.x * 4 + w;         // 8192 waves
    float4 cv[8];
    #pragma unroll
    for (int it = 0; it < 8; ++it)
        cv[it] = *(const float4*)(concat + (it * 64 + lane) * 4);
    float lm = -INFINITY, ls = 0.f;
    for (int v = gw; v < V; v += 8192) {
        const float* row = out_w + (size_t)v * (2 * H);
        float s = 0.f;
        #pragma unroll
        for (int it = 0; it < 8; ++it) {
            int elem = (it * 64 + lane) * 4;
            s += dot4(*(const float4*)(row + elem), cv[it]);
        }
        #pragma unroll
        for (int off = 32; off; off >>= 1) s += __shfl_xor(s, off);
        s += out_b[v];
        if (lane == 0) logits[v] = s;
        float Mn = fmaxf(lm, s);
        ls = ls * expf(lm - Mn) + expf(s - Mn);
        lm = Mn;
    }
    if (lane == 0) { mw[w] = lm; sw[w] = ls; }
    __syncthreads();
    if (threadIdx.x == 0) {
        float m = mw[0], s = sw[0];
        #pragma unroll
        for (int k = 1; k < 4; ++k) {
            float Mn = fmaxf(m, mw[k]);
            s = s * expf(m - Mn) + sw[k] * expf(mw[k] - Mn);
            m = Mn;
        }
        red[blockIdx.x] = m;
        red[2048 + blockIdx.x] = s;
    }
}

// ---------------- K6: reduce 2048 LSE partials + write. grid=197 x 256 -------
__global__ __launch_bounds__(256) void k_write(const float* __restrict__ logits,
        const float* __restrict__ red, float* __restrict__ out) {
    __shared__ float smv[4], ssv[4];
    const int t = threadIdx.x, w = t >> 6, lane = t & 63;
    float m = -INFINITY, s = 0.f;
    #pragma unroll
    for (int k = 0; k < 8; ++k) {
        int i = t * 8 + k;
        float m2 = red[i], s2 = red[2048 + i];
        float Mn = fmaxf(m, m2);
        s = s * expf(m - Mn) + s2 * expf(m2 - Mn);
        m = Mn;
    }
    #pragma unroll
    for (int off = 32; off; off >>= 1) {
        float m2 = __shfl_xor(m, off), s2 = __shfl_xor(s, off);
        float Mn = fmaxf(m, m2);
        s = s * expf(m - Mn) + s2 * expf(m2 - Mn);
        m = Mn;
    }
    if (lane == 0) { smv[w] = m; ssv[w] = s; }
    __syncthreads();
    float M = fmaxf(fmaxf(smv[0], smv[1]), fmaxf(smv[2], smv[3]));
    float S = ssv[0] * expf(smv[0] - M) + ssv[1] * expf(smv[1] - M) +
              ssv[2] * expf(smv[2] - M) + ssv[3] * expf(smv[3] - M);
    const float C = M + logf(S);
    const int v = blockIdx.x * 256 + t;
    if (v < V) out[v] = logits[v] - C;
}

extern "C" void kernel_launch(void* const* d_in, const int* in_sizes, int n_in,
                              void* d_out, int out_size, void* d_ws, size_t ws_size,
                              hipStream_t stream) {
    const int*   idx    = (const int*)d_in[0];
    const float* hidden = (const float*)d_in[1];
    const float* enc    = (const float*)d_in[2];
    const float* emb    = (const float*)d_in[3];
    const float* w_ih   = (const float*)d_in[4];
    const float* w_hh   = (const float*)d_in[5];
    const float* b_ih   = (const float*)d_in[6];
    const float* b_hh   = (const float*)d_in[7];
    const float* out_w  = (const float*)d_in[8];
    const float* out_b  = (const float*)d_in[9];
    float* out = (float*)d_out;        // [V] log_softmax | [H] h_new

    float* ws      = (float*)d_ws;
    float* concat  = ws;               // [2048] ctx | h_new
    float* scores  = ws + 2048;        // [4096]
    float* sb      = ws + 6144;        // [256]  per-block sum(e)
    unsigned int* gmax = (unsigned int*)(ws + 6400);   // [1]
    float* red     = ws + 6656;        // [4096] m[2048] | s[2048]
    float* partial = ws + 16384;       // [256*1024]
    float* logits  = ws + 278528;      // [50257]

    k_gru<<<512, 256, 0, stream>>>(idx, hidden, emb, w_ih, w_hh, b_ih, b_hh,
                                   concat, out + V, gmax);
    k_scores<<<L / 4, 256, 0, stream>>>(enc, concat, scores, gmax);
    k_ctx_partial<<<256, 256, 0, stream>>>(enc, scores, gmax, partial, sb);
    k_ctx_reduce<<<4, 256, 0, stream>>>(partial, sb, concat);
    k_logits<<<2048, 256, 0, stream>>>(out_w, out_b, concat, logits, red);
    k_write<<<(V + 255) / 256, 256, 0, stream>>>(logits, red, out);
}